// Round 6
// baseline (865.628 us; speedup 1.0000x reference)
//
#include <hip/hip_runtime.h>

typedef unsigned short ushort_t;
typedef __attribute__((ext_vector_type(8))) short short8;
typedef __attribute__((ext_vector_type(4))) float floatx4;
typedef __attribute__((ext_vector_type(2))) float floatx2;

#define N_NODES 8192
#define N_EDGES 262144
#define D_FEAT 512
#define NHID 32
#define LATENT 16

#define ADJ_OFF 0
#define FEAT_OFF (8192*8192)
#define Z_OFF (8192*8192 + 8192*512)

#define GCN_BLOCKS 512

static __device__ __forceinline__ ushort_t f2bf(float f) {
    unsigned int u = __float_as_uint(f);
    unsigned int r = u + 0x7fffu + ((u >> 16) & 1u);  // RNE
    return (ushort_t)(r >> 16);
}

// Device-scope grid barrier (CG grid.sync pattern). Counter monotonically
// increases; target = GCN_BLOCKS * phase. Counter zeroed by k_enc (prior
// dispatch in stream order).
static __device__ __forceinline__ void gbar(int* bar, int target) {
    __threadfence();
    __syncthreads();
    if (threadIdx.x == 0) {
        __hip_atomic_fetch_add(bar, 1, __ATOMIC_ACQ_REL, __HIP_MEMORY_SCOPE_AGENT);
        while (__hip_atomic_load(bar, __ATOMIC_ACQUIRE, __HIP_MEMORY_SCOPE_AGENT) < target) {
            __builtin_amdgcn_s_sleep(8);
        }
    }
    __syncthreads();
    __threadfence();
}

// ---------------------------------------------------------------------------
// K_enc: xwg = feat @ Wg1 ; he1 = relu(feat @ We1 + be1) ; zx = relu(he1@We2+be2)
// Also zeroes counts[] and the grid-barrier counter for k_gcn.
// ---------------------------------------------------------------------------
__global__ __launch_bounds__(256) void k_enc(const float* __restrict__ feat,
                                             const float* __restrict__ Wg1,
                                             const float* __restrict__ We1,
                                             const float* __restrict__ be1,
                                             const float* __restrict__ We2,
                                             const float* __restrict__ be2,
                                             float* __restrict__ xwg,
                                             float* __restrict__ zxf,
                                             int* __restrict__ counts,
                                             int* __restrict__ bar) {
    __shared__ float WL[32][64];   // [k][c]
    __shared__ float FL[32][33];   // [n][k]
    __shared__ float HE[32][33];
    int tid = threadIdx.x;
    int gid = blockIdx.x * 256 + tid;
    if (gid < N_NODES) counts[gid] = 0;
    if (gid == 0) *bar = 0;

    int cr = tid & 15;
    int nr = tid >> 4;
    int m0 = blockIdx.x * 32;
    float acc[2][4] = {};

    for (int kt = 0; kt < 16; kt++) {
        __syncthreads();
        {
            int i = tid;
            #pragma unroll
            for (int j = 0; j < 8; j++, i += 256) {
                int k = i >> 6, c = i & 63;
                int kg = kt * 32 + k;
                WL[k][c] = (c < 32) ? Wg1[kg * 32 + c] : We1[kg * 32 + (c - 32)];
            }
        }
        {
            int n = tid >> 3, q = tid & 7;
            float4 v = *(const float4*)(feat + (m0 + n) * 512 + kt * 32 + q * 4);
            FL[n][q * 4 + 0] = v.x; FL[n][q * 4 + 1] = v.y;
            FL[n][q * 4 + 2] = v.z; FL[n][q * 4 + 3] = v.w;
        }
        __syncthreads();
        #pragma unroll 4
        for (int k = 0; k < 32; k++) {
            float4 w = *(const float4*)&WL[k][cr * 4];
            float f0 = FL[nr * 2 + 0][k];
            float f1 = FL[nr * 2 + 1][k];
            acc[0][0] += f0 * w.x; acc[0][1] += f0 * w.y;
            acc[0][2] += f0 * w.z; acc[0][3] += f0 * w.w;
            acc[1][0] += f1 * w.x; acc[1][1] += f1 * w.y;
            acc[1][2] += f1 * w.z; acc[1][3] += f1 * w.w;
        }
    }
    int cg = cr * 4;
    if (cg < 32) {
        #pragma unroll
        for (int j = 0; j < 2; j++) {
            float4 v = make_float4(acc[j][0], acc[j][1], acc[j][2], acc[j][3]);
            *(float4*)(xwg + (m0 + nr * 2 + j) * 32 + cg) = v;
        }
    } else {
        int hc = cg - 32;
        #pragma unroll
        for (int j = 0; j < 2; j++) {
            #pragma unroll
            for (int t = 0; t < 4; t++) {
                float v = acc[j][t] + be1[hc + t];
                HE[nr * 2 + j][hc + t] = v > 0.f ? v : 0.f;
            }
        }
    }
    __syncthreads();
    int n = tid >> 3, j0 = (tid & 7) * 2;
    float s0 = be2[j0], s1 = be2[j0 + 1];
    #pragma unroll 8
    for (int cc = 0; cc < 32; cc++) {
        float h = HE[n][cc];
        s0 += h * We2[cc * 16 + j0];
        s1 += h * We2[cc * 16 + j0 + 1];
    }
    s0 = s0 > 0.f ? s0 : 0.f;
    s1 = s1 > 0.f ? s1 : 0.f;
    *(float2*)(zxf + (m0 + n) * 16 + j0) = make_float2(s0, s1);
}

// ---------------------------------------------------------------------------
// K_gcn: hist -> scan -> scatter -> agg1(+h@Wg2) -> agg2(z emit), fused with
// device-scope grid barriers. 512 blocks x 256 thr (2 blocks/CU co-resident).
// ---------------------------------------------------------------------------
__global__ __launch_bounds__(256, 2) void k_gcn(const int* __restrict__ esrc,
                                                const int* __restrict__ edst,
                                                const float* __restrict__ ew,
                                                const float* __restrict__ xwg,
                                                const float* __restrict__ bg1,
                                                const float* __restrict__ Wg2,
                                                const float* __restrict__ bg2,
                                                const float* __restrict__ zxf,
                                                int* __restrict__ counts,
                                                int* __restrict__ offs,
                                                int* __restrict__ cursor,
                                                int2* __restrict__ sedge,
                                                float* __restrict__ hw2,
                                                ushort_t* __restrict__ zbf,
                                                float* __restrict__ zout,
                                                int* __restrict__ bar) {
    __shared__ int ps[256];
    __shared__ float hsh[16][33];
    int tid = threadIdx.x;
    int b = blockIdx.x;

    // phase 1: histogram (512 edges per block)
    int e0 = b * 512;
    #pragma unroll
    for (int r = 0; r < 2; r++) {
        int e = e0 + r * 256 + tid;
        atomicAdd(&counts[edst[e]], 1);
    }
    gbar(bar, GCN_BLOCKS);

    // phase 2: exclusive scan of counts (block 0; 256 thr x 32 vals)
    if (b == 0) {
        int base = tid * 32;
        int loc[32];
        int s = 0;
        #pragma unroll
        for (int j = 0; j < 32; j++) { loc[j] = s; s += counts[base + j]; }
        ps[tid] = s;
        __syncthreads();
        for (int off = 1; off < 256; off <<= 1) {
            int v = ps[tid];
            int a = (tid >= off) ? ps[tid - off] : 0;
            __syncthreads();
            ps[tid] = v + a;
            __syncthreads();
        }
        int excl = tid ? ps[tid - 1] : 0;
        #pragma unroll
        for (int j = 0; j < 32; j++) {
            int o = excl + loc[j];
            offs[base + j] = o;
            cursor[base + j] = o;
        }
    }
    gbar(bar, 2 * GCN_BLOCKS);

    // phase 3: scatter (counting sort by dst)
    #pragma unroll
    for (int r = 0; r < 2; r++) {
        int e = e0 + r * 256 + tid;
        int d = edst[e];
        int pos = atomicAdd(&cursor[d], 1);
        sedge[pos] = make_int2(esrc[e], __float_as_int(ew[e]));
    }
    gbar(bar, 3 * GCN_BLOCKS);

    // phase 4: agg1 — 16 nodes/block (2 passes of 8 nodes x 32 lanes)
    {
        int ln = tid >> 5, c = tid & 31;
        for (int pass = 0; pass < 2; pass++) {
            int n = b * 16 + pass * 8 + ln;
            int st = offs[n], en = st + counts[n];
            float acc = 0.f;
            int i = st;
            for (; i + 4 <= en; i += 4) {
                int2 q0 = sedge[i], q1 = sedge[i + 1], q2 = sedge[i + 2], q3 = sedge[i + 3];
                float v0 = __int_as_float(q0.y) * xwg[q0.x * 32 + c];
                float v1 = __int_as_float(q1.y) * xwg[q1.x * 32 + c];
                float v2 = __int_as_float(q2.y) * xwg[q2.x * 32 + c];
                float v3 = __int_as_float(q3.y) * xwg[q3.x * 32 + c];
                acc += (v0 + v1) + (v2 + v3);
            }
            for (; i < en; i++) {
                int2 q = sedge[i];
                acc += __int_as_float(q.y) * xwg[q.x * 32 + c];
            }
            float h = acc + bg1[c];
            hsh[pass * 8 + ln][c] = h > 0.f ? h : 0.f;
        }
        __syncthreads();
        // hw2 = h @ Wg2 : 16 nodes x 16 cols
        int n2 = tid >> 4, j = tid & 15;
        float s2 = 0.f;
        #pragma unroll 8
        for (int cc = 0; cc < 32; cc++) s2 += hsh[n2][cc] * Wg2[cc * 16 + j];
        hw2[(b * 16 + n2) * 16 + j] = s2;
    }
    gbar(bar, 4 * GCN_BLOCKS);

    // phase 5: agg2 — 16 nodes/block x 16 lanes; emit z (f32) + zbf (bf16)
    {
        int ln = tid >> 4, c = tid & 15;
        int n = b * 16 + ln;
        int st = offs[n], en = st + counts[n];
        float acc = 0.f;
        int i = st;
        for (; i + 4 <= en; i += 4) {
            int2 q0 = sedge[i], q1 = sedge[i + 1], q2 = sedge[i + 2], q3 = sedge[i + 3];
            float v0 = __int_as_float(q0.y) * hw2[q0.x * 16 + c];
            float v1 = __int_as_float(q1.y) * hw2[q1.x * 16 + c];
            float v2 = __int_as_float(q2.y) * hw2[q2.x * 16 + c];
            float v3 = __int_as_float(q3.y) * hw2[q3.x * 16 + c];
            acc += (v0 + v1) + (v2 + v3);
        }
        for (; i < en; i++) {
            int2 q = sedge[i];
            acc += __int_as_float(q.y) * hw2[q.x * 16 + c];
        }
        float za = acc + bg2[c];
        za = za > 0.f ? za : 0.f;
        float zx = zxf[n * 16 + c];
        zout[n * 32 + c] = za;
        zout[n * 32 + 16 + c] = zx;
        zbf[n * 32 + c] = f2bf(za);
        zbf[n * 32 + 16 + c] = f2bf(zx);
    }
}

// ---------------------------------------------------------------------------
// K_out: blocks [0,2048): adj = sigmoid(z z^T) via bf16 MFMA;
//        blocks [2048,2560): feat_recon = relu(relu(zx@Wd1+bd1)@Wd2+bd2).
// ---------------------------------------------------------------------------
__global__ __launch_bounds__(256) void k_out(const ushort_t* __restrict__ zbf,
                                             const float* __restrict__ zxf,
                                             const float* __restrict__ Wd1,
                                             const float* __restrict__ bd1,
                                             const float* __restrict__ Wd2,
                                             const float* __restrict__ bd2,
                                             float* __restrict__ out) {
    __shared__ float ZL[16][17];
    __shared__ float HT[16][33];
    int tid = threadIdx.x;
    if (blockIdx.x < 2048) {
        float* adj = out + ADJ_OFF;
        int l = tid & 63;
        int wv = tid >> 6;
        int strip = blockIdx.x & 15;
        int rt = (blockIdx.x >> 4) * 4 + wv;
        int q = l >> 4, cl = l & 15;
        int m0 = rt * 16, c0 = strip * 512;
        short8 a = *(const short8*)(zbf + (m0 + cl) * 32 + q * 8);
        for (int g = 0; g < 8; g++) {
            int cb = c0 + g * 64;
            short8 b0 = *(const short8*)(zbf + (cb + 4 * cl + 0) * 32 + q * 8);
            short8 b1 = *(const short8*)(zbf + (cb + 4 * cl + 1) * 32 + q * 8);
            short8 b2 = *(const short8*)(zbf + (cb + 4 * cl + 2) * 32 + q * 8);
            short8 b3 = *(const short8*)(zbf + (cb + 4 * cl + 3) * 32 + q * 8);
            floatx4 zv = {0, 0, 0, 0};
            floatx4 a0 = __builtin_amdgcn_mfma_f32_16x16x32_bf16(a, b0, zv, 0, 0, 0);
            floatx4 a1 = __builtin_amdgcn_mfma_f32_16x16x32_bf16(a, b1, zv, 0, 0, 0);
            floatx4 a2 = __builtin_amdgcn_mfma_f32_16x16x32_bf16(a, b2, zv, 0, 0, 0);
            floatx4 a3 = __builtin_amdgcn_mfma_f32_16x16x32_bf16(a, b3, zv, 0, 0, 0);
            #pragma unroll
            for (int r = 0; r < 4; r++) {
                floatx4 v;
                v.x = 1.f / (1.f + __expf(-a0[r]));
                v.y = 1.f / (1.f + __expf(-a1[r]));
                v.z = 1.f / (1.f + __expf(-a2[r]));
                v.w = 1.f / (1.f + __expf(-a3[r]));
                int row = m0 + q * 4 + r;
                __builtin_nontemporal_store(v, (floatx4*)(adj + (size_t)row * 8192 + cb + 4 * cl));
            }
        }
    } else {
        float* outF = out + FEAT_OFF;
        int m0 = (blockIdx.x - 2048) * 16;
        {
            int n = tid >> 4, k = tid & 15;
            ZL[n][k] = zxf[(m0 + n) * 16 + k];
        }
        __syncthreads();
        {
            int o = tid * 2;
            int n = o >> 5, c = o & 31;
            float s0 = bd1[c], s1 = bd1[c + 1];
            #pragma unroll
            for (int k = 0; k < 16; k++) {
                float z = ZL[n][k];
                s0 += z * Wd1[k * 32 + c];
                s1 += z * Wd1[k * 32 + c + 1];
            }
            HT[n][c] = s0 > 0.f ? s0 : 0.f;
            HT[n][c + 1] = s1 > 0.f ? s1 : 0.f;
        }
        __syncthreads();
        int c2 = tid * 2;
        floatx2 acc[16];
        #pragma unroll
        for (int n = 0; n < 16; n++) acc[n] = (floatx2){0.f, 0.f};
        for (int k = 0; k < 32; k++) {
            float2 w = *(const float2*)(Wd2 + k * 512 + c2);
            #pragma unroll
            for (int n = 0; n < 16; n++) {
                float t = HT[n][k];
                acc[n].x += t * w.x;
                acc[n].y += t * w.y;
            }
        }
        float b0 = bd2[c2], b1 = bd2[c2 + 1];
        #pragma unroll
        for (int n = 0; n < 16; n++) {
            float s0 = acc[n].x + b0, s1 = acc[n].y + b1;
            s0 = s0 > 0.f ? s0 : 0.f;
            s1 = s1 > 0.f ? s1 : 0.f;
            floatx2 pk = {s0, s1};
            __builtin_nontemporal_store(pk, (floatx2*)(outF + (size_t)(m0 + n) * 512 + c2));
        }
    }
}

// ---------------------------------------------------------------------------
extern "C" void kernel_launch(void* const* d_in, const int* in_sizes, int n_in,
                              void* d_out, int out_size, void* d_ws, size_t ws_size,
                              hipStream_t stream) {
    const float* feat = (const float*)d_in[0];
    const int* esrc = (const int*)d_in[1];
    const int* edst = (const int*)d_in[2];
    const float* ew = (const float*)d_in[3];
    const float* Wg1 = (const float*)d_in[4];
    const float* bg1 = (const float*)d_in[5];
    const float* Wg2 = (const float*)d_in[6];
    const float* bg2 = (const float*)d_in[7];
    const float* We1 = (const float*)d_in[8];
    const float* be1 = (const float*)d_in[9];
    const float* We2 = (const float*)d_in[10];
    const float* be2 = (const float*)d_in[11];
    const float* Wd1 = (const float*)d_in[12];
    const float* bd1 = (const float*)d_in[13];
    const float* Wd2 = (const float*)d_in[14];
    const float* bd2 = (const float*)d_in[15];
    float* out = (float*)d_out;

    char* ws = (char*)d_ws;
    float* xwg      = (float*)(ws + 0);            // 1 MB
    float* zxf      = (float*)(ws + 1048576);      // 512 KB
    float* hw2      = (float*)(ws + 1572864);      // 512 KB
    ushort_t* zbf   = (ushort_t*)(ws + 2097152);   // 512 KB
    int* counts     = (int*)(ws + 2621440);        // 32 KB
    int* offs       = (int*)(ws + 2654208);        // 32 KB
    int* cursor     = (int*)(ws + 2686976);        // 32 KB
    int* bar        = (int*)(ws + 2719744);        // 4 B (+pad)
    int2* sedge     = (int2*)(ws + 2719872);       // 2 MB

    k_enc<<<N_NODES / 32, 256, 0, stream>>>(feat, Wg1, We1, be1, We2, be2,
                                            xwg, zxf, counts, bar);
    k_gcn<<<GCN_BLOCKS, 256, 0, stream>>>(esrc, edst, ew, xwg, bg1, Wg2, bg2, zxf,
                                          counts, offs, cursor, sedge, hw2,
                                          zbf, out + Z_OFF, bar);
    k_out<<<2048 + 512, 256, 0, stream>>>(zbf, zxf, Wd1, bd1, Wd2, bd2, out);
}

// Round 7
// 440.827 us; speedup vs baseline: 1.9636x; 1.9636x over previous
//
#include <hip/hip_runtime.h>

typedef unsigned short ushort_t;
typedef __attribute__((ext_vector_type(8))) short short8;
typedef __attribute__((ext_vector_type(4))) float floatx4;
typedef __attribute__((ext_vector_type(2))) float floatx2;

#define N_NODES 8192
#define N_EDGES 262144
#define D_FEAT 512
#define NHID 32
#define LATENT 16

#define ADJ_OFF 0
#define FEAT_OFF (8192*8192)
#define Z_OFF (8192*8192 + 8192*512)

static __device__ __forceinline__ ushort_t f2bf(float f) {
    unsigned int u = __float_as_uint(f);
    unsigned int r = u + 0x7fffu + ((u >> 16) & 1u);  // RNE
    return (ushort_t)(r >> 16);
}

// sigmoid via native exp2 + rcp (no IEEE div sequence); |err| ~1e-7
static __device__ __forceinline__ float fsig(float x) {
    float e = __builtin_amdgcn_exp2f(x * -1.44269504f);
    return __builtin_amdgcn_rcpf(1.f + e);
}

// ---------------------------------------------------------------------------
// K_enc: xwg = feat @ Wg1 ; he1 = relu(feat @ We1 + be1) ; zx = relu(he1@We2+be2)
// 512 blocks x 16 nodes (2 blocks/CU). thread = 1 node x 4 cols of 64-concat.
// Also zeroes counts[] for k_hist (which runs after).
// ---------------------------------------------------------------------------
__global__ __launch_bounds__(256) void k_enc(const float* __restrict__ feat,
                                             const float* __restrict__ Wg1,
                                             const float* __restrict__ We1,
                                             const float* __restrict__ be1,
                                             const float* __restrict__ We2,
                                             const float* __restrict__ be2,
                                             float* __restrict__ xwg,
                                             float* __restrict__ zxf,
                                             int* __restrict__ counts) {
    __shared__ float WL[32][64];   // 8 KB   [k][c]
    __shared__ float FL[16][36];   // 2.3 KB [n][k]
    __shared__ float HE[16][33];
    int tid = threadIdx.x;
    int gid = blockIdx.x * 256 + tid;
    if (gid < N_NODES) counts[gid] = 0;

    int n = tid >> 4;              // 0..15 node
    int cr = tid & 15;             // col quad (4 cols)
    int m0 = blockIdx.x * 16;
    float acc[4] = {};

    for (int kt = 0; kt < 16; kt++) {
        __syncthreads();
        // stage WL: 32 k x 64 c
        {
            int i = tid;
            #pragma unroll
            for (int j = 0; j < 8; j++, i += 256) {
                int k = i >> 6, c = i & 63;
                int kg = kt * 32 + k;
                WL[k][c] = (c < 32) ? Wg1[kg * 32 + c] : We1[kg * 32 + (c - 32)];
            }
        }
        // stage FL: 16 n x 32 k (128 threads x float4)
        if (tid < 128) {
            int nn = tid >> 3, q = tid & 7;
            float4 v = *(const float4*)(feat + (m0 + nn) * 512 + kt * 32 + q * 4);
            FL[nn][q * 4 + 0] = v.x; FL[nn][q * 4 + 1] = v.y;
            FL[nn][q * 4 + 2] = v.z; FL[nn][q * 4 + 3] = v.w;
        }
        __syncthreads();
        #pragma unroll 4
        for (int k = 0; k < 32; k++) {
            float4 w = *(const float4*)&WL[k][cr * 4];
            float f0 = FL[n][k];
            acc[0] += f0 * w.x; acc[1] += f0 * w.y;
            acc[2] += f0 * w.z; acc[3] += f0 * w.w;
        }
    }
    int cg = cr * 4;
    if (cg < 32) {
        float4 v = make_float4(acc[0], acc[1], acc[2], acc[3]);
        *(float4*)(xwg + (m0 + n) * 32 + cg) = v;
    } else {
        int hc = cg - 32;
        #pragma unroll
        for (int t = 0; t < 4; t++) {
            float v = acc[t] + be1[hc + t];
            HE[n][hc + t] = v > 0.f ? v : 0.f;
        }
    }
    __syncthreads();
    // zx = relu(he1 @ We2 + be2): 16 n x 16 j, one value per thread
    {
        int j = cr;
        float s = be2[j];
        #pragma unroll 8
        for (int cc = 0; cc < 32; cc++) s += HE[n][cc] * We2[cc * 16 + j];
        zxf[(m0 + n) * 16 + j] = s > 0.f ? s : 0.f;
    }
}

// ---------------------------------------------------------------------------
// CSR build: histogram, scan, scatter (counting sort by dst)
// ---------------------------------------------------------------------------
__global__ __launch_bounds__(256) void k_hist(const int* __restrict__ edst, int* __restrict__ counts) {
    int e = blockIdx.x * 256 + threadIdx.x;
    atomicAdd(&counts[edst[e]], 1);
}

__global__ __launch_bounds__(1024) void k_scan(const int* __restrict__ counts,
                                               int* __restrict__ offs, int* __restrict__ cursor) {
    __shared__ int sdata[1024];
    int t = threadIdx.x;
    int base = t * 8;
    int c[8], local[8];
    int s = 0;
    #pragma unroll
    for (int j = 0; j < 8; j++) { c[j] = counts[base + j]; }
    #pragma unroll
    for (int j = 0; j < 8; j++) { local[j] = s; s += c[j]; }
    sdata[t] = s;
    __syncthreads();
    for (int off = 1; off < 1024; off <<= 1) {
        int v = sdata[t];
        int add = (t >= off) ? sdata[t - off] : 0;
        __syncthreads();
        sdata[t] = v + add;
        __syncthreads();
    }
    int excl = (t == 0) ? 0 : sdata[t - 1];
    #pragma unroll
    for (int j = 0; j < 8; j++) {
        int o = excl + local[j];
        offs[base + j] = o;
        cursor[base + j] = o;
    }
}

__global__ __launch_bounds__(256) void k_scatter(const int* __restrict__ esrc,
                                                 const int* __restrict__ edst,
                                                 const float* __restrict__ ew,
                                                 int* __restrict__ cursor,
                                                 int2* __restrict__ sedge) {
    int e = blockIdx.x * 256 + threadIdx.x;
    int d = edst[e];
    int pos = atomicAdd(&cursor[d], 1);
    sedge[pos] = make_int2(esrc[e], __float_as_int(ew[e]));
}

// ---------------------------------------------------------------------------
// K_agg1: h = relu(segsum(xwg[src]*w) + bg1); hw2 = h @ Wg2
// block = 8 nodes x 32 lanes; unroll-4 batched gather
// ---------------------------------------------------------------------------
__global__ __launch_bounds__(256) void k_agg1(const float* __restrict__ xwg,
                                              const int* __restrict__ offs,
                                              const int* __restrict__ counts,
                                              const int2* __restrict__ sedge,
                                              const float* __restrict__ bg1,
                                              const float* __restrict__ Wg2,
                                              float* __restrict__ hw2) {
    __shared__ float hsh[8][33];
    int ln = threadIdx.x >> 5, c = threadIdx.x & 31;
    int n = blockIdx.x * 8 + ln;
    int st = offs[n], en = st + counts[n];
    float acc = 0.f;
    int i = st;
    for (; i + 4 <= en; i += 4) {
        int2 e0 = sedge[i], e1 = sedge[i + 1], e2 = sedge[i + 2], e3 = sedge[i + 3];
        float s0 = __int_as_float(e0.y) * xwg[e0.x * 32 + c];
        float s1 = __int_as_float(e1.y) * xwg[e1.x * 32 + c];
        float s2 = __int_as_float(e2.y) * xwg[e2.x * 32 + c];
        float s3 = __int_as_float(e3.y) * xwg[e3.x * 32 + c];
        acc += (s0 + s1) + (s2 + s3);
    }
    for (; i < en; i++) {
        int2 e = sedge[i];
        acc += __int_as_float(e.y) * xwg[e.x * 32 + c];
    }
    float h = acc + bg1[c];
    hsh[ln][c] = h > 0.f ? h : 0.f;
    __syncthreads();
    if (threadIdx.x < 128) {
        int l2 = threadIdx.x >> 4, j = threadIdx.x & 15;
        float s2 = 0.f;
        #pragma unroll 8
        for (int cc = 0; cc < 32; cc++) s2 += hsh[l2][cc] * Wg2[cc * 16 + j];
        hw2[(blockIdx.x * 8 + l2) * 16 + j] = s2;
    }
}

// ---------------------------------------------------------------------------
// K_agg2: za = relu(segsum(hw2[src]*w) + bg2); z output (f32) + zbf (bf16)
// block = 16 nodes x 16 lanes
// ---------------------------------------------------------------------------
__global__ __launch_bounds__(256) void k_agg2(const float* __restrict__ hw2,
                                              const int* __restrict__ offs,
                                              const int* __restrict__ counts,
                                              const int2* __restrict__ sedge,
                                              const float* __restrict__ bg2,
                                              const float* __restrict__ zxf,
                                              ushort_t* __restrict__ zbf,
                                              float* __restrict__ zout) {
    int ln = threadIdx.x >> 4, c = threadIdx.x & 15;
    int n = blockIdx.x * 16 + ln;
    int st = offs[n], en = st + counts[n];
    float acc = 0.f;
    int i = st;
    for (; i + 4 <= en; i += 4) {
        int2 e0 = sedge[i], e1 = sedge[i + 1], e2 = sedge[i + 2], e3 = sedge[i + 3];
        float s0 = __int_as_float(e0.y) * hw2[e0.x * 16 + c];
        float s1 = __int_as_float(e1.y) * hw2[e1.x * 16 + c];
        float s2 = __int_as_float(e2.y) * hw2[e2.x * 16 + c];
        float s3 = __int_as_float(e3.y) * hw2[e3.x * 16 + c];
        acc += (s0 + s1) + (s2 + s3);
    }
    for (; i < en; i++) {
        int2 e = sedge[i];
        acc += __int_as_float(e.y) * hw2[e.x * 16 + c];
    }
    float za = acc + bg2[c];
    za = za > 0.f ? za : 0.f;
    float zx = zxf[n * 16 + c];
    zout[n * 32 + c] = za;
    zout[n * 32 + 16 + c] = zx;
    zbf[n * 32 + c] = f2bf(za);
    zbf[n * 32 + 16 + c] = f2bf(zx);
}

// ---------------------------------------------------------------------------
// K_out: blocks [0,2048): adj = sigmoid(z z^T) via bf16 MFMA + fast sigmoid;
//        blocks [2048,2560): feat_recon = relu(relu(zx@Wd1+bd1)@Wd2+bd2).
// ---------------------------------------------------------------------------
__global__ __launch_bounds__(256) void k_out(const ushort_t* __restrict__ zbf,
                                             const float* __restrict__ zxf,
                                             const float* __restrict__ Wd1,
                                             const float* __restrict__ bd1,
                                             const float* __restrict__ Wd2,
                                             const float* __restrict__ bd2,
                                             float* __restrict__ out) {
    __shared__ float ZL[16][17];
    __shared__ float HT[16][33];
    int tid = threadIdx.x;
    if (blockIdx.x < 2048) {
        float* adj = out + ADJ_OFF;
        int l = tid & 63;
        int wv = tid >> 6;
        int strip = blockIdx.x & 15;
        int rt = (blockIdx.x >> 4) * 4 + wv;
        int q = l >> 4, cl = l & 15;
        int m0 = rt * 16, c0 = strip * 512;
        short8 a = *(const short8*)(zbf + (m0 + cl) * 32 + q * 8);
        for (int g = 0; g < 8; g++) {
            int cb = c0 + g * 64;
            short8 b0 = *(const short8*)(zbf + (cb + 4 * cl + 0) * 32 + q * 8);
            short8 b1 = *(const short8*)(zbf + (cb + 4 * cl + 1) * 32 + q * 8);
            short8 b2 = *(const short8*)(zbf + (cb + 4 * cl + 2) * 32 + q * 8);
            short8 b3 = *(const short8*)(zbf + (cb + 4 * cl + 3) * 32 + q * 8);
            floatx4 zv = {0, 0, 0, 0};
            floatx4 a0 = __builtin_amdgcn_mfma_f32_16x16x32_bf16(a, b0, zv, 0, 0, 0);
            floatx4 a1 = __builtin_amdgcn_mfma_f32_16x16x32_bf16(a, b1, zv, 0, 0, 0);
            floatx4 a2 = __builtin_amdgcn_mfma_f32_16x16x32_bf16(a, b2, zv, 0, 0, 0);
            floatx4 a3 = __builtin_amdgcn_mfma_f32_16x16x32_bf16(a, b3, zv, 0, 0, 0);
            #pragma unroll
            for (int r = 0; r < 4; r++) {
                floatx4 v;
                v.x = fsig(a0[r]);
                v.y = fsig(a1[r]);
                v.z = fsig(a2[r]);
                v.w = fsig(a3[r]);
                int row = m0 + q * 4 + r;
                __builtin_nontemporal_store(v, (floatx4*)(adj + (size_t)row * 8192 + cb + 4 * cl));
            }
        }
    } else {
        float* outF = out + FEAT_OFF;
        int m0 = (blockIdx.x - 2048) * 16;
        {
            int n = tid >> 4, k = tid & 15;
            ZL[n][k] = zxf[(m0 + n) * 16 + k];
        }
        __syncthreads();
        {
            int o = tid * 2;
            int n = o >> 5, c = o & 31;
            float s0 = bd1[c], s1 = bd1[c + 1];
            #pragma unroll
            for (int k = 0; k < 16; k++) {
                float z = ZL[n][k];
                s0 += z * Wd1[k * 32 + c];
                s1 += z * Wd1[k * 32 + c + 1];
            }
            HT[n][c] = s0 > 0.f ? s0 : 0.f;
            HT[n][c + 1] = s1 > 0.f ? s1 : 0.f;
        }
        __syncthreads();
        int c2 = tid * 2;
        floatx2 acc[16];
        #pragma unroll
        for (int n = 0; n < 16; n++) acc[n] = (floatx2){0.f, 0.f};
        for (int k = 0; k < 32; k++) {
            float2 w = *(const float2*)(Wd2 + k * 512 + c2);
            #pragma unroll
            for (int n = 0; n < 16; n++) {
                float t = HT[n][k];
                acc[n].x += t * w.x;
                acc[n].y += t * w.y;
            }
        }
        float b0 = bd2[c2], b1 = bd2[c2 + 1];
        #pragma unroll
        for (int n = 0; n < 16; n++) {
            float s0 = acc[n].x + b0, s1 = acc[n].y + b1;
            s0 = s0 > 0.f ? s0 : 0.f;
            s1 = s1 > 0.f ? s1 : 0.f;
            floatx2 pk = {s0, s1};
            __builtin_nontemporal_store(pk, (floatx2*)(outF + (size_t)(m0 + n) * 512 + c2));
        }
    }
}

// ---------------------------------------------------------------------------
extern "C" void kernel_launch(void* const* d_in, const int* in_sizes, int n_in,
                              void* d_out, int out_size, void* d_ws, size_t ws_size,
                              hipStream_t stream) {
    const float* feat = (const float*)d_in[0];
    const int* esrc = (const int*)d_in[1];
    const int* edst = (const int*)d_in[2];
    const float* ew = (const float*)d_in[3];
    const float* Wg1 = (const float*)d_in[4];
    const float* bg1 = (const float*)d_in[5];
    const float* Wg2 = (const float*)d_in[6];
    const float* bg2 = (const float*)d_in[7];
    const float* We1 = (const float*)d_in[8];
    const float* be1 = (const float*)d_in[9];
    const float* We2 = (const float*)d_in[10];
    const float* be2 = (const float*)d_in[11];
    const float* Wd1 = (const float*)d_in[12];
    const float* bd1 = (const float*)d_in[13];
    const float* Wd2 = (const float*)d_in[14];
    const float* bd2 = (const float*)d_in[15];
    float* out = (float*)d_out;

    char* ws = (char*)d_ws;
    float* xwg      = (float*)(ws + 0);            // 1 MB
    float* zxf      = (float*)(ws + 1048576);      // 512 KB
    float* hw2      = (float*)(ws + 1572864);      // 512 KB
    ushort_t* zbf   = (ushort_t*)(ws + 2097152);   // 512 KB
    int* counts     = (int*)(ws + 2621440);        // 32 KB
    int* offs       = (int*)(ws + 2654208);        // 32 KB
    int* cursor     = (int*)(ws + 2686976);        // 32 KB
    int2* sedge     = (int2*)(ws + 2719744);       // 2 MB

    k_enc<<<N_NODES / 16, 256, 0, stream>>>(feat, Wg1, We1, be1, We2, be2,
                                            xwg, zxf, counts);
    k_hist<<<N_EDGES / 256, 256, 0, stream>>>(edst, counts);
    k_scan<<<1, 1024, 0, stream>>>(counts, offs, cursor);
    k_scatter<<<N_EDGES / 256, 256, 0, stream>>>(esrc, edst, ew, cursor, sedge);
    k_agg1<<<N_NODES / 8, 256, 0, stream>>>(xwg, offs, counts, sedge, bg1, Wg2, hw2);
    k_agg2<<<N_NODES / 16, 256, 0, stream>>>(hw2, offs, counts, sedge, bg2, zxf,
                                             zbf, out + Z_OFF);
    k_out<<<2048 + 512, 256, 0, stream>>>(zbf, zxf, Wd1, bd1, Wd2, bd2, out);
}